// Round 5
// baseline (118.229 us; speedup 1.0000x reference)
//
#include <hip/hip_runtime.h>
#include <math.h>

#define N_OCT  32
#define N_SMP  32768
#define N_PAIR 64          // B*E = 4*16
#define BPP    32          // blocks per pair: 1024 samples/block, 4/thread

// ---------------------------------------------------------------------------
// R11: single kernel, per-pair barrier with MINIMAL device-coherent traffic.
//  R10 post-mortem: agent-scope stores for the full 8.4 MB of `out` turned
//  coalesced write-back lines into per-lane write-through transactions
//  (+25 us). Correctness held, so keep the protocol but shrink its footprint:
//  ONLY the 4 B per-block max and one u32 counter per pair are device-
//  coherent. `out` is written once, normalized, with normal coalesced
//  float4 stores (nothing ever reads it from another XCD).
//  Barrier: tid0 agent-stores its block max -> vmcnt(0) -> atomicAdd(cnt)
//  -> polls cnt (relaxed agent load, s_sleep backoff, bounded 2^16 so a
//  broken protocol FAILS loudly instead of hanging). Siblings of a pair do
//  identical work (same ng) -> skew ~0 -> polls resolve in a few hundred ns.
//  Unlike R8's 65 us grid sync: 64 independent lines, 32 arrivals each, no
//  fences, no two-phase rocclr protocol.
//  Deadlock-free by pigeonhole: __launch_bounds__(256,8) caps VGPR at 64 ->
//  8 blocks/CU -> capacity 2048 = grid; 64*31=1984 < 2048 means some pair's
//  cohort is always fully resident -> completes -> frees slots.
//  Counter lives in poisoned ws (fill is unconditional per R9 -> free);
//  baseline P probed from an untouched ws word; wrap-safe (cnt-P)>=32 test.
//  Sample map: 4 consecutive samples/thread -> one float4 store. Bit-safe:
//  per-sample octave-sum order unchanged; block fmax over the same 1024
//  values in different order is exact. Output bit-identical to R7.
// ---------------------------------------------------------------------------
__global__ __launch_bounds__(256, 8) void f0res_fused(
    const float* __restrict__ f0_in,
    const float* __restrict__ dec_in,
    const float* __restrict__ fs_in,
    float* __restrict__ out,
    unsigned int* __restrict__ ws)
{
    __shared__ __align__(16) float sw[N_OCT];
    __shared__ __align__(16) float sa[N_OCT];
    __shared__ int s_ng;
    __shared__ float wm[4];
    __shared__ float s_inv;

    const int pair = blockIdx.x >> 5;
    const int blk  = blockIdx.x & (BPP - 1);
    const int tid  = threadIdx.x;

    unsigned int* cnt  = ws;                           // [64] u32 counters
    float*        bmax = (float*)(ws + 256);           // byte 1K: [64][32] f32
    const unsigned int* probe = ws + (1u << 18);       // byte 1M: untouched

    // ---- in-block setup (lanes 0-31 of wave 0) ----
    if (tid < N_OCT) {
        const float minf   = (float)(20.0 / 11025.0);
        const float frange = (float)(3000.0 / 11025.0 - 20.0 / 11025.0);
        const float pif    = 3.14159265358979323846f;
        const float INV2PI = 0.15915494309189535f;

        float f0 = fabsf(f0_in[pair]);
        float fs = fs_in[pair];
        float x  = dec_in[pair];

        float s1 = 1.0f / (1.0f + expf(-x));      // double sigmoid (ref quirk)
        float s2 = 1.0f / (1.0f + expf(-s1));
        float d  = 0.01f + s2 * (float)(0.99 * 0.99);
        float ld = logf(d + 1e-12f);
        float f0p = (minf + f0 * frange) * pif;

        // sequential fp32 cumsums — bit-match the reference rounding order
        float fac = 0.0f, acl = 0.0f, myfac = 0.0f, myacl = 0.0f;
#pragma unroll
        for (int o = 0; o < N_OCT; ++o) {
            fac += fs;
            acl += ld;
            if (o == tid) { myfac = fac; myacl = acl; }
        }
        float f0s = f0p * myfac;
        const bool act = (f0s < 1.0f);            // monotone -> prefix mask
        sw[tid] = act ? f0s * INV2PI : 0.0f;      // revolutions; sin(0)=0
        sa[tid] = expf(myacl);                    // d^(o+1)

        unsigned long long bal = __ballot(act);   // lanes 32-63 inactive -> 0
        if (tid == 0) s_ng = (__popcll(bal) + 3) >> 2;   // active float4 groups
    }
    __syncthreads();

    const int ng = s_ng;                          // uniform per block

    const int   s0 = (blk << 10) + (tid << 2);    // 4 consecutive samples
    const float t0 = (float)(s0 + 1);             // t = s+1, exact in fp32
    const float t1 = (float)(s0 + 2);
    const float t2 = (float)(s0 + 3);
    const float t3 = (float)(s0 + 4);

    float acc0 = 0.0f, acc1 = 0.0f, acc2 = 0.0f, acc3 = 0.0f;

    const float4* w4 = (const float4*)sw;
    const float4* a4 = (const float4*)sa;
    for (int i = 0; i < ng; ++i) {
        const float4 wv = w4[i];                  // ds_read_b128 broadcast
        const float4 av = a4[i];
        const float wr[4] = { wv.x, wv.y, wv.z, wv.w };
        const float ar[4] = { av.x, av.y, av.z, av.w };
#pragma unroll
        for (int j = 0; j < 4; ++j) {
            const float w = wr[j], a = ar[j];
            acc0 = fmaf(a, __builtin_amdgcn_sinf(__builtin_amdgcn_fractf(w * t0)), acc0);
            acc1 = fmaf(a, __builtin_amdgcn_sinf(__builtin_amdgcn_fractf(w * t1)), acc1);
            acc2 = fmaf(a, __builtin_amdgcn_sinf(__builtin_amdgcn_fractf(w * t2)), acc2);
            acc3 = fmaf(a, __builtin_amdgcn_sinf(__builtin_amdgcn_fractf(w * t3)), acc3);
        }
    }

    // ---- block max (same 1024 values as R7; fmax order-insensitive) ----
    float av_ = fmaxf(fmaxf(fabsf(acc0), fabsf(acc1)),
                      fmaxf(fabsf(acc2), fabsf(acc3)));
#pragma unroll
    for (int m = 32; m >= 1; m >>= 1)
        av_ = fmaxf(av_, __shfl_xor(av_, m, 64));
    if ((tid & 63) == 0) wm[tid >> 6] = av_;
    __syncthreads();

    // ---- per-pair barrier: 4 B agent store + counter add + bounded poll ----
    if (tid == 0) {
        const unsigned int P = probe[0];          // poison baseline this iter
        float bm = fmaxf(fmaxf(wm[0], wm[1]), fmaxf(wm[2], wm[3]));
        __hip_atomic_store(&bmax[(pair << 5) + blk], bm,
                           __ATOMIC_RELAXED, __HIP_MEMORY_SCOPE_AGENT);
        asm volatile("s_waitcnt vmcnt(0)" ::: "memory");   // release 4 B
        atomicAdd(&cnt[pair], 1u);                         // device-scope RMW
        unsigned int it = 0;
        while ((unsigned int)(__hip_atomic_load(&cnt[pair], __ATOMIC_RELAXED,
                                 __HIP_MEMORY_SCOPE_AGENT) - P) < 32u) {
            if (++it > (1u << 16)) break;          // loud-fail, never hang
            __builtin_amdgcn_s_sleep(8);
        }
    }
    __syncthreads();                               // block-wide acquire

    // ---- pair max (32 agent loads, one 128 B transaction), normalize ----
    {
        float v = 0.0f;
        if (tid < 32)
            v = __hip_atomic_load(&bmax[(pair << 5) + tid],
                                  __ATOMIC_RELAXED, __HIP_MEMORY_SCOPE_AGENT);
        if (tid < 64) {
#pragma unroll
            for (int m = 16; m >= 1; m >>= 1)
                v = fmaxf(v, __shfl_xor(v, m, 64));
            if (tid == 0) s_inv = 1.0f / (v + 1e-8f);
        }
    }
    __syncthreads();
    const float inv = s_inv;

    // ---- single normalized write: normal coalesced float4 (write-back) ----
    float4 r = { acc0 * inv, acc1 * inv, acc2 * inv, acc3 * inv };
    *(float4*)(out + pair * N_SMP + s0) = r;
}

extern "C" void kernel_launch(void* const* d_in, const int* in_sizes, int n_in,
                              void* d_out, int out_size, void* d_ws, size_t ws_size,
                              hipStream_t stream) {
    const float* f0  = (const float*)d_in[0];
    const float* dec = (const float*)d_in[1];
    const float* fs  = (const float*)d_in[2];
    float* out = (float*)d_out;
    unsigned int* ws = (unsigned int*)d_ws;

    f0res_fused<<<N_PAIR * BPP, 256, 0, stream>>>(f0, dec, fs, out, ws);
}

// Round 6
// 69.354 us; speedup vs baseline: 1.7047x; 1.7047x over previous
//
#include <hip/hip_runtime.h>
#include <math.h>

#define N_OCT  32
#define N_SMP  32768
#define N_PAIR 64          // B*E = 4*16
#define BPP    32          // blocks per pair: 1024 samples/block, 4/thread
#define CNT_STRIDE 64      // one u32 counter per 256-B line (R12 fix)

// ---------------------------------------------------------------------------
// R12: R11 with ONE change — per-pair counters padded to one per 256-B line.
//  R11 post-mortem: 64 counters packed in 2 cachelines meant 2048 device-
//  scope RMWs + all polling loads serialized on 2 lines at the coherence
//  point (~70 us, same as R8's single-line rocclr grid sync). Padding gives
//  64 independent lines / MALL channels: 32 serialized RMWs per line ~1-2 us,
//  fully overlapped across the 64 pairs.
//  Everything else identical to R11 (which was CORRECT, absmax bit-exact):
//   - only 4 B/block max + 1 u32/pair counter are device-coherent;
//     out is written once, normalized, coalesced float4 write-back.
//   - release = agent store -> vmcnt(0) -> device atomicAdd;
//     acquire = bounded poll (s_sleep backoff) -> __syncthreads.
//   - deadlock-free by pigeonhole: __launch_bounds__(256,8) -> 8 blocks/CU
//     -> whole 2048-block grid resident; poll bound 2^16 -> loud-fail.
//   - counter NOT restored: R11 passing without restore proves the ws
//     poison-fill re-runs every iteration (probe gives fresh baseline P).
//   - osc body: R7's (active-octave truncation, 4 FMA chains, exact
//     sequential-cumsum prologue). Output bit-identical to R7.
// ---------------------------------------------------------------------------
__global__ __launch_bounds__(256, 8) void f0res_fused(
    const float* __restrict__ f0_in,
    const float* __restrict__ dec_in,
    const float* __restrict__ fs_in,
    float* __restrict__ out,
    unsigned int* __restrict__ ws)
{
    __shared__ __align__(16) float sw[N_OCT];
    __shared__ __align__(16) float sa[N_OCT];
    __shared__ int s_ng;
    __shared__ float wm[4];
    __shared__ float s_inv;

    const int pair = blockIdx.x >> 5;
    const int blk  = blockIdx.x & (BPP - 1);
    const int tid  = threadIdx.x;

    unsigned int* cnt  = ws;                           // [64 * 64] u32, padded
    float*        bmax = (float*)(ws + (1u << 14));    // byte 64K: [64][32] f32
    const unsigned int* probe = ws + (1u << 18);       // byte 1M: untouched

    // ---- in-block setup (lanes 0-31 of wave 0) ----
    if (tid < N_OCT) {
        const float minf   = (float)(20.0 / 11025.0);
        const float frange = (float)(3000.0 / 11025.0 - 20.0 / 11025.0);
        const float pif    = 3.14159265358979323846f;
        const float INV2PI = 0.15915494309189535f;

        float f0 = fabsf(f0_in[pair]);
        float fs = fs_in[pair];
        float x  = dec_in[pair];

        float s1 = 1.0f / (1.0f + expf(-x));      // double sigmoid (ref quirk)
        float s2 = 1.0f / (1.0f + expf(-s1));
        float d  = 0.01f + s2 * (float)(0.99 * 0.99);
        float ld = logf(d + 1e-12f);
        float f0p = (minf + f0 * frange) * pif;

        // sequential fp32 cumsums — bit-match the reference rounding order
        float fac = 0.0f, acl = 0.0f, myfac = 0.0f, myacl = 0.0f;
#pragma unroll
        for (int o = 0; o < N_OCT; ++o) {
            fac += fs;
            acl += ld;
            if (o == tid) { myfac = fac; myacl = acl; }
        }
        float f0s = f0p * myfac;
        const bool act = (f0s < 1.0f);            // monotone -> prefix mask
        sw[tid] = act ? f0s * INV2PI : 0.0f;      // revolutions; sin(0)=0
        sa[tid] = expf(myacl);                    // d^(o+1)

        unsigned long long bal = __ballot(act);   // lanes 32-63 inactive -> 0
        if (tid == 0) s_ng = (__popcll(bal) + 3) >> 2;   // active float4 groups
    }
    __syncthreads();

    const int ng = s_ng;                          // uniform per block

    const int   s0 = (blk << 10) + (tid << 2);    // 4 consecutive samples
    const float t0 = (float)(s0 + 1);             // t = s+1, exact in fp32
    const float t1 = (float)(s0 + 2);
    const float t2 = (float)(s0 + 3);
    const float t3 = (float)(s0 + 4);

    float acc0 = 0.0f, acc1 = 0.0f, acc2 = 0.0f, acc3 = 0.0f;

    const float4* w4 = (const float4*)sw;
    const float4* a4 = (const float4*)sa;
    for (int i = 0; i < ng; ++i) {
        const float4 wv = w4[i];                  // ds_read_b128 broadcast
        const float4 av = a4[i];
        const float wr[4] = { wv.x, wv.y, wv.z, wv.w };
        const float ar[4] = { av.x, av.y, av.z, av.w };
#pragma unroll
        for (int j = 0; j < 4; ++j) {
            const float w = wr[j], a = ar[j];
            acc0 = fmaf(a, __builtin_amdgcn_sinf(__builtin_amdgcn_fractf(w * t0)), acc0);
            acc1 = fmaf(a, __builtin_amdgcn_sinf(__builtin_amdgcn_fractf(w * t1)), acc1);
            acc2 = fmaf(a, __builtin_amdgcn_sinf(__builtin_amdgcn_fractf(w * t2)), acc2);
            acc3 = fmaf(a, __builtin_amdgcn_sinf(__builtin_amdgcn_fractf(w * t3)), acc3);
        }
    }

    // ---- block max (same 1024 values as R7; fmax order-insensitive) ----
    float av_ = fmaxf(fmaxf(fabsf(acc0), fabsf(acc1)),
                      fmaxf(fabsf(acc2), fabsf(acc3)));
#pragma unroll
    for (int m = 32; m >= 1; m >>= 1)
        av_ = fmaxf(av_, __shfl_xor(av_, m, 64));
    if ((tid & 63) == 0) wm[tid >> 6] = av_;
    __syncthreads();

    // ---- per-pair barrier: 4 B agent store + padded counter + bounded poll
    if (tid == 0) {
        const unsigned int P = probe[0];          // poison baseline this iter
        unsigned int* c = &cnt[pair * CNT_STRIDE];
        float bm = fmaxf(fmaxf(wm[0], wm[1]), fmaxf(wm[2], wm[3]));
        __hip_atomic_store(&bmax[(pair << 5) + blk], bm,
                           __ATOMIC_RELAXED, __HIP_MEMORY_SCOPE_AGENT);
        asm volatile("s_waitcnt vmcnt(0)" ::: "memory");   // release 4 B
        atomicAdd(c, 1u);                                  // device-scope RMW
        unsigned int it = 0;
        while ((unsigned int)(__hip_atomic_load(c, __ATOMIC_RELAXED,
                                 __HIP_MEMORY_SCOPE_AGENT) - P) < 32u) {
            if (++it > (1u << 16)) break;          // loud-fail, never hang
            __builtin_amdgcn_s_sleep(8);
        }
    }
    __syncthreads();                               // block-wide acquire

    // ---- pair max (32 agent loads, one 128 B line), normalize ----
    {
        float v = 0.0f;
        if (tid < 32)
            v = __hip_atomic_load(&bmax[(pair << 5) + tid],
                                  __ATOMIC_RELAXED, __HIP_MEMORY_SCOPE_AGENT);
        if (tid < 64) {
#pragma unroll
            for (int m = 16; m >= 1; m >>= 1)
                v = fmaxf(v, __shfl_xor(v, m, 64));
            if (tid == 0) s_inv = 1.0f / (v + 1e-8f);
        }
    }
    __syncthreads();
    const float inv = s_inv;

    // ---- single normalized write: normal coalesced float4 (write-back) ----
    float4 r = { acc0 * inv, acc1 * inv, acc2 * inv, acc3 * inv };
    *(float4*)(out + pair * N_SMP + s0) = r;
}

extern "C" void kernel_launch(void* const* d_in, const int* in_sizes, int n_in,
                              void* d_out, int out_size, void* d_ws, size_t ws_size,
                              hipStream_t stream) {
    const float* f0  = (const float*)d_in[0];
    const float* dec = (const float*)d_in[1];
    const float* fs  = (const float*)d_in[2];
    float* out = (float*)d_out;
    unsigned int* ws = (unsigned int*)d_ws;

    f0res_fused<<<N_PAIR * BPP, 256, 0, stream>>>(f0, dec, fs, out, ws);
}